// Round 14
// baseline (163.386 us; speedup 1.0000x reference)
//
#include <hip/hip_runtime.h>
#include <hip/hip_bf16.h>
#include <math.h>

typedef __attribute__((ext_vector_type(8))) short short8;
typedef __attribute__((ext_vector_type(4))) short s4;
typedef __attribute__((ext_vector_type(4))) float f32x4;

#define NJ 24

// ---- ws image: per-fragment 1KB blocks (64 lanes x 16B), lane-major ----
// W1image row 13 = b1 (bias-as-K: x[13]=1), row13 col77 = 1.0 (h[77] regenerator)
// W2image row 77 = b2
#define F1_J   7680
#define F2_OFF (NJ*F1_J)
#define F2_J   6144
#define FP_OFF (F2_OFF + NJ*F2_J)
#define IMG_SHORTS (FP_OFF + 36*512)        // 350208 shorts = 700416 B

// operand-swapped MFMA: A = weights [n][k], B = activations [k][batch]
#define MFMA(A,B,C) __builtin_amdgcn_mfma_f32_16x16x32_bf16((A),(B),(C),0,0,0)

__constant__ int ORD[24] = {0,1,4,7,10, 2,5,8,11, 3,6,9, 12,15, 13,16,18,20,22, 14,17,19,21,23};
__constant__ int PSL[24] = {2,0,1,1,1,  0,1,1,1,  0,0,0,  0,1,   0,1,1,1,1,    0,0,0,0,0};
__constant__ int SSL[24] = {0,1,1,1,-1, 1,1,1,-1, 0,0,0,  1,-1,  1,1,1,1,-1,   0,0,0,0,-1};

__device__ __forceinline__ short f2bf(float f) {
  union { float f; unsigned u; } v; v.f = f;
  unsigned r = v.u + 0x7FFFu + ((v.u >> 16) & 1u);
  return (short)(r >> 16);
}
__device__ __forceinline__ short sbf(float f) {
  __hip_bfloat16 h = __float2bfloat16(f);
  return *reinterpret_cast<short*>(&h);
}
__device__ __forceinline__ short8 pk8(f32x4 lo, f32x4 hi) {
  union { short8 s; unsigned u[4]; } r;
  asm("v_cvt_pk_bf16_f32 %0, %1, %2" : "=v"(r.u[0]) : "v"(lo[0]), "v"(lo[1]));
  asm("v_cvt_pk_bf16_f32 %0, %1, %2" : "=v"(r.u[1]) : "v"(lo[2]), "v"(lo[3]));
  asm("v_cvt_pk_bf16_f32 %0, %1, %2" : "=v"(r.u[2]) : "v"(hi[0]), "v"(hi[1]));
  asm("v_cvt_pk_bf16_f32 %0, %1, %2" : "=v"(r.u[3]) : "v"(hi[2]), "v"(hi[3]));
  return r.s;
}
__device__ __forceinline__ s4 pk4(f32x4 v) {
  union { s4 s; unsigned u[2]; } r;
  asm("v_cvt_pk_bf16_f32 %0, %1, %2" : "=v"(r.u[0]) : "v"(v[0]), "v"(v[1]));
  asm("v_cvt_pk_bf16_f32 %0, %1, %2" : "=v"(r.u[1]) : "v"(v[2]), "v"(v[3]));
  return r.s;
}
__device__ __forceinline__ f32x4 relu4(f32x4 v) {
  f32x4 r; r[0]=fmaxf(v[0],0.f); r[1]=fmaxf(v[1],0.f);
  r[2]=fmaxf(v[2],0.f); r[3]=fmaxf(v[3],0.f); return r;
}

__global__ __launch_bounds__(256) void prep_kernel(
    const float* __restrict__ W1, const float* __restrict__ W2,
    const float* __restrict__ Wp, const float* __restrict__ b1,
    const float* __restrict__ b2, short* __restrict__ img) {
  int t = blockIdx.x * 256 + threadIdx.x;
  if (t >= IMG_SHORTS) return;
  float v = 0.f;
  if (t < F2_OFF) {
    int i = t / F1_J, r = t % F1_J;
    int blk = r >> 9, q = r & 511;
    int ln = q >> 3, e = q & 7;
    int nt = blk / 3, s = blk - nt*3;
    int n  = nt*16 + (ln & 15);
    int kp = s*32 + (ln >> 4)*8 + e;
    if (kp == 13) {
      v = (n < 77) ? b1[i*77 + n] : (n == 77 ? 1.f : 0.f);
    } else if (n < 77) {
      if (kp < 13)                  v = W1[i*5929 + kp*77 + n];
      else if (kp >= 16 && kp < 80) v = W1[i*5929 + (kp-3)*77 + n];
    }
  } else if (t < FP_OFF) {
    int u = t - F2_OFF;
    int i = u / F2_J, r = u % F2_J;
    int blk = r >> 9, q = r & 511;
    int ln = q >> 3, e = q & 7;
    int nt = blk / 3, s = blk - nt*3;
    int n  = nt*16 + (ln & 15);
    int k  = s*32 + (ln >> 4)*8 + e;
    if (k < 77)       v = W2[i*4928 + k*64 + n];
    else if (k == 77) v = b2[i*64 + n];
  } else {
    int u = t - FP_OFF;
    int blk = u >> 9, q = u & 511;
    int ln = q >> 3, e = q & 7;
    int nt = blk / 9, s = blk - nt*9;
    int n  = nt*16 + (ln & 15);
    int kp = s*32 + (ln >> 4)*8 + e;
    int j, w;
    if (kp < 216) { j = kp / 9;       w = kp % 9; }
    else          { j = (kp-216) / 3; w = 9 + (kp-216) % 3; }
    v = Wp[(j*12 + w)*64 + n];
  }
  img[t] = f2bf(v);
}

// bt(4 dword) + stage(4 dwordx4, vaddr-only 64b addresses) ; census 8 per wave.
#define ISSUE_BTSTG() \
  asm volatile( \
    "global_load_dword %0, %8, off\n" \
    "global_load_dword %1, %9, off\n" \
    "global_load_dword %2, %9, off offset:4\n" \
    "global_load_dword %3, %9, off offset:8\n" \
    "global_load_dwordx4 %4, %10, off\n" \
    "global_load_dwordx4 %5, %11, off\n" \
    "global_load_dwordx4 %6, %12, off\n" \
    "global_load_dwordx4 %7, %13, off\n" \
    : "=&v"(d0),"=&v"(d1),"=&v"(d2),"=&v"(d3), \
      "=&v"(sg0),"=&v"(sg1),"=&v"(sg2),"=&v"(sg3) \
    : "v"(aA), "v"(aB), "v"(aS0), "v"(aS1), "v"(aS2), "v"(aS3) \
    : "memory")

#define WAITV(N) do { asm volatile("s_waitcnt vmcnt(" #N ")" ::: "memory"); \
                      __builtin_amdgcn_sched_barrier(0); } while(0)
#define LGKM0_BAR() do { asm volatile("s_waitcnt lgkmcnt(0)" ::: "memory"); \
                         __builtin_amdgcn_s_barrier(); \
                         asm volatile("" ::: "memory"); } while(0)

// stage base for block b of joint jj (bytes into img)
__device__ __forceinline__ unsigned long long stg_base(
    unsigned long long img_u, int jj, int b) {
  if (b < 15)      return img_u + (unsigned long long)jj*15360ull + (unsigned long long)b*1024ull;
  else if (b < 27) return img_u + 368640ull + (unsigned long long)jj*12288ull + (unsigned long long)(b-15)*1024ull;
  else             return img_u + 368640ull + (unsigned long long)jj*12288ull;   // dummy
}

// 512 threads = 8 waves x 16 rows. Weights WG-shared in LDS, double-buffered,
// staged via reg roundtrip with exact counted vmcnt; ONE raw barrier per joint.
__global__ __launch_bounds__(512, 2) void enc_kernel(
    const float* __restrict__ pose, const float* __restrict__ rel,
    const float* __restrict__ bp,  const short* __restrict__ img,
    float* __restrict__ out) {
  __shared__ __align__(16) short lds[68608];    // 137,216 B -> 1 WG/CU
  short* wlds = lds;                            // 2 bufs x 28 blocks x 512 shorts
  short* priv = lds + 28672;

  const int tid  = threadIdx.x;
  const int lane = tid & 63;
  const int wv   = tid >> 6;
  short* featL = priv + wv*4992;                // 3 slots x [16][72] = 3456
  short* hL    = featL + 3456;                  // [16][80] = 1280
  short* btL   = featL + 4736;                  // [16][16] = 256

  const int cl  = lane & 15;
  const int g   = lane >> 4;
  const int rw0 = blockIdx.x*128 + wv*16;
  const short8 zz = {0,0,0,0,0,0,0,0};
  const unsigned long long img_u  = (unsigned long long)img;
  const unsigned long long pose_u = (unsigned long long)pose;
  const unsigned long long rel_u  = (unsigned long long)rel;
  const unsigned long long voff = (unsigned long long)((unsigned)lane << 4);
  const int btr = lane >> 2, btq = lane & 3;    // 4 lanes per row
  const unsigned long long btP = pose_u + (unsigned long long)(rw0 + btr)*864ull;
  const unsigned long long btR = rel_u  + (unsigned long long)(rw0 + btr)*288ull;

  // wave's 4 stage blocks
  const int b0 = wv*4, b1i_ = wv*4+1, b2i_ = wv*4+2, b3i_ = wv*4+3;
  short* sd0 = wlds + ((b0   > 26 ? 27 : b0  )*512) + lane*8;
  short* sd1 = wlds + ((b1i_ > 26 ? 27 : b1i_)*512) + lane*8;
  short* sd2 = wlds + ((b2i_ > 26 ? 27 : b2i_)*512) + lane*8;
  short* sd3 = wlds + ((b3i_ > 26 ? 27 : b3i_)*512) + lane*8;

  float d0, d1, d2, d3;
  short8 sg0, sg1, sg2, sg3;

  // ---- prologue: bt[0] via compiler loads ----
  {
    const float* pb = pose + (size_t)(rw0 + btr)*216;
    const float* rb = rel  + (size_t)(rw0 + btr)*72;
    if (btq == 0) {
      f32x4 v = *(const f32x4*)pb;
      *(s4*)(btL + btr*16) = pk4(v);
    } else if (btq == 1) {
      f32x4 v = *(const f32x4*)(pb + 4);
      *(s4*)(btL + btr*16 + 4) = pk4(v);
    } else if (btq == 2) {
      float r0 = rb[0], r1 = rb[1], r2 = rb[2];
      float nv = sqrtf(r0*r0 + r1*r1 + r2*r2);
      short8 w;
      w[0]=sbf(pb[8]); w[1]=sbf(r0); w[2]=sbf(r1); w[3]=sbf(r2);
      w[4]=sbf(nv); w[5]=(short)0x3F80; w[6]=0; w[7]=0;
      *(short8*)(btL + btr*16 + 8) = w;
    }
  }
  f32x4 bpv[4];
#pragma unroll
  for (int nt = 0; nt < 4; ++nt) bpv[nt] = *(const f32x4*)(bp + nt*16 + g*4);

  // ---- root: WpT x bonefeat -> feat slot 2 (compiler loads, pre-asm) ----
  f32x4 racc[4] = {};
  {
    const float* pr = pose + (size_t)(rw0 + cl)*216;
    const float* rr = rel  + (size_t)(rw0 + cl)*72;
    const short8* fpg = (const short8*)(img + FP_OFF) + lane;
    short8 av[9];
#pragma unroll
    for (int s = 0; s < 9; ++s) {
      int k0 = s*32 + g*8;
      const float* sp = (k0 < 216) ? (pr + k0) : (rr + (k0 - 216));
      av[s] = pk8(*(const f32x4*)sp, *(const f32x4*)(sp + 4));
    }
#pragma unroll
    for (int nt = 0; nt < 4; ++nt) {
      short8 fwp[9];
#pragma unroll
      for (int s = 0; s < 9; ++s) fwp[s] = fpg[(nt*9 + s)*64];
#pragma unroll
      for (int s = 0; s < 9; ++s) racc[nt] = MFMA(fwp[s], av[s], racc[nt]);
    }
  }
#pragma unroll
  for (int nt = 0; nt < 4; ++nt) {
    f32x4 v = racc[nt];
    v[0]+=bpv[nt][0]; v[1]+=bpv[nt][1]; v[2]+=bpv[nt][2]; v[3]+=bpv[nt][3];
    *(s4*)(featL + 2*1152 + cl*72 + nt*16 + g*4) = pk4(v);
  }

  // ---- prologue stage: weights of ORD[0]=0 into buf0 ----
  {
    unsigned long long aS0 = stg_base(img_u, 0, b0)   + voff;
    unsigned long long aS1 = stg_base(img_u, 0, b1i_) + voff;
    unsigned long long aS2 = stg_base(img_u, 0, b2i_) + voff;
    unsigned long long aS3 = stg_base(img_u, 0, b3i_) + voff;
    unsigned long long aA = btP, aB = btP + 4ull;    // dummy bt (safe addrs)
    ISSUE_BTSTG();
    WAITV(0);
    *(short8*)sd0 = sg0; *(short8*)sd1 = sg1;
    *(short8*)sd2 = sg2; *(short8*)sd3 = sg3;
  }
  LGKM0_BAR();

  // ---- main DFS loop ----
#pragma unroll 1
  for (int p = 0; p < NJ; ++p) {
    const int j  = ORD[p];
    const int ps = PSL[p];
    const int ss = SSL[p];
    const int jn = (p < NJ-1) ? ORD[p+1] : 0;

    const short* wb = wlds + (p & 1)*14336 + lane*8;   // this joint's weights

    // B: activation fragments (wave-private LDS)
    const short* fb = featL + ps*1152 + cl*72;
    short8 a0 = (g < 2) ? *(const short8*)(btL + cl*16 + g*8)
                        : *(const short8*)(fb + (g-2)*8);
    short8 a1 = *(const short8*)(fb + 16 + g*8);
    short8 a2 = (g < 2) ? *(const short8*)(fb + 48 + g*8) : zz;

    // D: GEMM1 from shared LDS weights
#pragma unroll
    for (int nt = 0; nt < 5; ++nt) {
      short8 w0 = *(const short8*)(wb + (nt*3+0)*512);
      short8 w1 = *(const short8*)(wb + (nt*3+1)*512);
      short8 w2 = *(const short8*)(wb + (nt*3+2)*512);
      f32x4 c = {0,0,0,0};
      c = MFMA(w0, a0, c);
      c = MFMA(w1, a1, c);
      c = MFMA(w2, a2, c);
      *(s4*)(hL + cl*80 + nt*16 + g*4) = pk4(relu4(c));
    }
    // E: h fragments
    short8 h0 = *(const short8*)(hL + cl*80 + g*8);
    short8 h1 = *(const short8*)(hL + cl*80 + 32 + g*8);
    short8 h2 = (g < 2) ? *(const short8*)(hL + cl*80 + 64 + g*8) : zz;

    // asm: bt(jn) 4 dwords + stage(jn weights) 4 x4s -> census 8
    {
      unsigned long long aS0 = stg_base(img_u, jn, b0)   + voff;
      unsigned long long aS1 = stg_base(img_u, jn, b1i_) + voff;
      unsigned long long aS2 = stg_base(img_u, jn, b2i_) + voff;
      unsigned long long aS3 = stg_base(img_u, jn, b3i_) + voff;
      unsigned long long aA, aB;
      if (btq == 0)      { aA = btP + (unsigned)(jn*36);      aB = aA + 4ull; }
      else if (btq == 1) { aA = btP + (unsigned)(jn*36) + 16; aB = aA + 4ull; }
      else               { aA = btP + (unsigned)(jn*36) + 32; aB = btR + (unsigned)(jn*12); }
      ISSUE_BTSTG();
    }
    WAITV(4);                                   // bt arrived (stage in flight)

    // decode bt(jn) -> btL
    if (btq == 0)      *(s4*)(btL + btr*16)     = pk4((f32x4){d0,d1,d2,d3});
    else if (btq == 1) *(s4*)(btL + btr*16 + 4) = pk4((f32x4){d0,d1,d2,d3});
    else if (btq == 2) {
      float nv = sqrtf(d1*d1 + d2*d2 + d3*d3);
      short8 w;
      w[0]=sbf(d0); w[1]=sbf(d1); w[2]=sbf(d2); w[3]=sbf(d3);
      w[4]=sbf(nv); w[5]=(short)0x3F80; w[6]=0; w[7]=0;
      *(short8*)(btL + btr*16 + 8) = w;
    }

    // I: GEMM2 + coalesced stores + feat writes
#pragma unroll
    for (int nt = 0; nt < 4; ++nt) {
      short8 w0 = *(const short8*)(wb + (15 + nt*3+0)*512);
      short8 w1 = *(const short8*)(wb + (15 + nt*3+1)*512);
      short8 w2 = *(const short8*)(wb + (15 + nt*3+2)*512);
      f32x4 c = {0,0,0,0};
      c = MFMA(w0, h0, c);
      c = MFMA(w1, h1, c);
      c = MFMA(w2, h2, c);
      f32x4 v = relu4(c);
      float* o = out + (size_t)(rw0 + cl)*1536 + (size_t)j*64 + nt*16 + g*4;
      __builtin_nontemporal_store(v, (f32x4*)o);
      if (ss >= 0)
        *(s4*)(featL + ss*1152 + cl*72 + nt*16 + g*4) = pk4(v);
    }

    if (p < NJ-1) {
      WAITV(4);                                 // stage arrived (stores in flight)
      *(short8*)((p & 1) ? sd0 : sd0 + 14336) = sg0;   // write into buf[(p+1)%2]
      *(short8*)((p & 1) ? sd1 : sd1 + 14336) = sg1;
      *(short8*)((p & 1) ? sd2 : sd2 + 14336) = sg2;
      *(short8*)((p & 1) ? sd3 : sd3 + 14336) = sg3;
      LGKM0_BAR();
    }
  }
}

extern "C" void kernel_launch(void* const* d_in, const int* in_sizes, int n_in,
                              void* d_out, int out_size, void* d_ws, size_t ws_size,
                              hipStream_t stream) {
  const float* pose = (const float*)d_in[0];
  const float* rel  = (const float*)d_in[1];
  const float* Wp   = (const float*)d_in[2];
  const float* bp   = (const float*)d_in[3];
  const float* W1   = (const float*)d_in[4];
  const float* b1   = (const float*)d_in[5];
  const float* W2   = (const float*)d_in[6];
  const float* b2   = (const float*)d_in[7];
  float* outp = (float*)d_out;
  short* img  = (short*)d_ws;
  const int Bn = in_sizes[0] / 216;
  prep_kernel<<<(IMG_SHORTS + 255)/256, 256, 0, stream>>>(W1, W2, Wp, b1, b2, img);
  enc_kernel<<<Bn/128, 512, 0, stream>>>(pose, rel, bp, img, outp);
}

// Round 15
// 160.111 us; speedup vs baseline: 1.0205x; 1.0205x over previous
//
#include <hip/hip_runtime.h>
#include <hip/hip_bf16.h>
#include <math.h>

typedef __attribute__((ext_vector_type(8))) short short8;
typedef __attribute__((ext_vector_type(4))) short s4;
typedef __attribute__((ext_vector_type(4))) float f32x4;

#define NJ 24

// ---- ws image: per-fragment 1KB blocks (64 lanes x 16B), lane-major ----
// W1image row 13 = b1 (bias-as-K: x[13]=1), row13 col77 = 1.0 (h[77] regenerator)
// W2image row 77 = b2
#define F1_J   7680
#define F2_OFF (NJ*F1_J)
#define F2_J   6144
#define FP_OFF (F2_OFF + NJ*F2_J)
#define IMG_SHORTS (FP_OFF + 36*512)        // 350208 shorts = 700416 B

// operand-swapped MFMA: A = weights [n][k], B = activations [k][batch]
#define MFMA(A,B,C) __builtin_amdgcn_mfma_f32_16x16x32_bf16((A),(B),(C),0,0,0)

__constant__ int ORD[24] = {0,1,4,7,10, 2,5,8,11, 3,6,9, 12,15, 13,16,18,20,22, 14,17,19,21,23};
__constant__ int PSL[24] = {2,0,1,1,1,  0,1,1,1,  0,0,0,  0,1,   0,1,1,1,1,    0,0,0,0,0};
__constant__ int SSL[24] = {0,1,1,1,-1, 1,1,1,-1, 0,0,0,  1,-1,  1,1,1,1,-1,   0,0,0,0,-1};

__device__ __forceinline__ short f2bf(float f) {
  union { float f; unsigned u; } v; v.f = f;
  unsigned r = v.u + 0x7FFFu + ((v.u >> 16) & 1u);
  return (short)(r >> 16);
}
__device__ __forceinline__ short sbf(float f) {
  __hip_bfloat16 h = __float2bfloat16(f);
  return *reinterpret_cast<short*>(&h);
}
__device__ __forceinline__ short8 pk8(f32x4 lo, f32x4 hi) {
  union { short8 s; unsigned u[4]; } r;
  asm("v_cvt_pk_bf16_f32 %0, %1, %2" : "=v"(r.u[0]) : "v"(lo[0]), "v"(lo[1]));
  asm("v_cvt_pk_bf16_f32 %0, %1, %2" : "=v"(r.u[1]) : "v"(lo[2]), "v"(lo[3]));
  asm("v_cvt_pk_bf16_f32 %0, %1, %2" : "=v"(r.u[2]) : "v"(hi[0]), "v"(hi[1]));
  asm("v_cvt_pk_bf16_f32 %0, %1, %2" : "=v"(r.u[3]) : "v"(hi[2]), "v"(hi[3]));
  return r.s;
}
__device__ __forceinline__ s4 pk4(f32x4 v) {
  union { s4 s; unsigned u[2]; } r;
  asm("v_cvt_pk_bf16_f32 %0, %1, %2" : "=v"(r.u[0]) : "v"(v[0]), "v"(v[1]));
  asm("v_cvt_pk_bf16_f32 %0, %1, %2" : "=v"(r.u[1]) : "v"(v[2]), "v"(v[3]));
  return r.s;
}
__device__ __forceinline__ f32x4 relu4(f32x4 v) {
  f32x4 r; r[0]=fmaxf(v[0],0.f); r[1]=fmaxf(v[1],0.f);
  r[2]=fmaxf(v[2],0.f); r[3]=fmaxf(v[3],0.f); return r;
}

__global__ __launch_bounds__(256) void prep_kernel(
    const float* __restrict__ W1, const float* __restrict__ W2,
    const float* __restrict__ Wp, const float* __restrict__ b1,
    const float* __restrict__ b2, short* __restrict__ img) {
  int t = blockIdx.x * 256 + threadIdx.x;
  if (t >= IMG_SHORTS) return;
  float v = 0.f;
  if (t < F2_OFF) {
    int i = t / F1_J, r = t % F1_J;
    int blk = r >> 9, q = r & 511;
    int ln = q >> 3, e = q & 7;
    int nt = blk / 3, s = blk - nt*3;
    int n  = nt*16 + (ln & 15);
    int kp = s*32 + (ln >> 4)*8 + e;
    if (kp == 13) {
      v = (n < 77) ? b1[i*77 + n] : (n == 77 ? 1.f : 0.f);
    } else if (n < 77) {
      if (kp < 13)                  v = W1[i*5929 + kp*77 + n];
      else if (kp >= 16 && kp < 80) v = W1[i*5929 + (kp-3)*77 + n];
    }
  } else if (t < FP_OFF) {
    int u = t - F2_OFF;
    int i = u / F2_J, r = u % F2_J;
    int blk = r >> 9, q = r & 511;
    int ln = q >> 3, e = q & 7;
    int nt = blk / 3, s = blk - nt*3;
    int n  = nt*16 + (ln & 15);
    int k  = s*32 + (ln >> 4)*8 + e;
    if (k < 77)       v = W2[i*4928 + k*64 + n];
    else if (k == 77) v = b2[i*64 + n];
  } else {
    int u = t - FP_OFF;
    int blk = u >> 9, q = u & 511;
    int ln = q >> 3, e = q & 7;
    int nt = blk / 9, s = blk - nt*9;
    int n  = nt*16 + (ln & 15);
    int kp = s*32 + (ln >> 4)*8 + e;
    int j, w;
    if (kp < 216) { j = kp / 9;       w = kp % 9; }
    else          { j = (kp-216) / 3; w = 9 + (kp-216) % 3; }
    v = Wp[(j*12 + w)*64 + n];
  }
  img[t] = f2bf(v);
}

// 15 W1 fragment loads (asm-pinned, 16B-aligned, in-bounds)
#define ISSUE_W1(JN) do { \
  unsigned long long _b = img_u + (unsigned long long)(JN)*15360ull; \
  asm volatile( \
    "global_load_dwordx4 %0, %15, %16\n"  "global_load_dwordx4 %1, %15, %16 offset:1024\n" \
    "global_load_dwordx4 %2, %15, %16 offset:2048\n" "global_load_dwordx4 %3, %15, %16 offset:3072\n" \
    "global_load_dwordx4 %4, %15, %17\n"  "global_load_dwordx4 %5, %15, %17 offset:1024\n" \
    "global_load_dwordx4 %6, %15, %17 offset:2048\n" "global_load_dwordx4 %7, %15, %17 offset:3072\n" \
    "global_load_dwordx4 %8, %15, %18\n"  "global_load_dwordx4 %9, %15, %18 offset:1024\n" \
    "global_load_dwordx4 %10, %15, %18 offset:2048\n" "global_load_dwordx4 %11, %15, %18 offset:3072\n" \
    "global_load_dwordx4 %12, %15, %19\n" "global_load_dwordx4 %13, %15, %19 offset:1024\n" \
    "global_load_dwordx4 %14, %15, %19 offset:2048\n" \
    : "=&v"(fw1[0]),"=&v"(fw1[1]),"=&v"(fw1[2]),"=&v"(fw1[3]),"=&v"(fw1[4]), \
      "=&v"(fw1[5]),"=&v"(fw1[6]),"=&v"(fw1[7]),"=&v"(fw1[8]),"=&v"(fw1[9]), \
      "=&v"(fw1[10]),"=&v"(fw1[11]),"=&v"(fw1[12]),"=&v"(fw1[13]),"=&v"(fw1[14]) \
    : "v"(voff), "s"(_b), "s"(_b+4096ull), "s"(_b+8192ull), "s"(_b+12288ull) \
    : "memory"); \
} while(0)

// 8 bt dword loads (4B-aligned, in-bounds) + 12 W2 x4 loads. Census: 20.
#define ISSUE_BTW2(J) do { \
  unsigned long long _b = img_u + 368640ull + (unsigned long long)(J)*12288ull; \
  asm volatile( \
    "global_load_dword %0, %20, off\n" \
    "global_load_dword %1, %20, off offset:4\n" \
    "global_load_dword %2, %20, off offset:8\n" \
    "global_load_dword %3, %20, off offset:12\n" \
    "global_load_dword %4, %21, %22\n" \
    "global_load_dword %5, %21, %22 offset:4\n" \
    "global_load_dword %6, %21, %22 offset:8\n" \
    "global_load_dword %7, %21, %22 offset:12\n" \
    "global_load_dwordx4 %8, %23, %24\n"  "global_load_dwordx4 %9, %23, %24 offset:1024\n" \
    "global_load_dwordx4 %10, %23, %24 offset:2048\n" "global_load_dwordx4 %11, %23, %24 offset:3072\n" \
    "global_load_dwordx4 %12, %23, %25\n" "global_load_dwordx4 %13, %23, %25 offset:1024\n" \
    "global_load_dwordx4 %14, %23, %25 offset:2048\n" "global_load_dwordx4 %15, %23, %25 offset:3072\n" \
    "global_load_dwordx4 %16, %23, %26\n" "global_load_dwordx4 %17, %23, %26 offset:1024\n" \
    "global_load_dwordx4 %18, %23, %26 offset:2048\n" "global_load_dwordx4 %19, %23, %26 offset:3072\n" \
    : "=&v"(d0),"=&v"(d1),"=&v"(d2),"=&v"(d3),"=&v"(d4),"=&v"(d5),"=&v"(d6),"=&v"(d7), \
      "=&v"(fw2[0]),"=&v"(fw2[1]),"=&v"(fw2[2]),"=&v"(fw2[3]),"=&v"(fw2[4]),"=&v"(fw2[5]), \
      "=&v"(fw2[6]),"=&v"(fw2[7]),"=&v"(fw2[8]),"=&v"(fw2[9]),"=&v"(fw2[10]),"=&v"(fw2[11]) \
    : "v"(aA), "v"(vB), "s"(pose_u), "v"(voff), \
      "s"(_b), "s"(_b+4096ull), "s"(_b+8192ull) \
    : "memory"); \
} while(0)

#define WAITV(N) do { asm volatile("s_waitcnt vmcnt(" #N ")" ::: "memory"); \
                      __builtin_amdgcn_sched_barrier(0); } while(0)

// 512 threads = 8 waves x 32 rows; 1 WG/CU (159,744 B LDS); grid = 256 = 1 cohort.
// One RAW s_barrier per joint phase-locks the 8 waves so their identical 27 KB
// weight reads dedupe in the CU's 32 KB L1. No waitcnt at the barrier; no
// cross-wave data -> pure rendezvous, pipelines stay in flight.
// Census: I:8 stores | A:20 (bt8+W2x12) | F:15 (W1 next); C=28, H=15, p0 peel 20.
__global__ __launch_bounds__(512, 2) void enc_kernel(
    const float* __restrict__ pose, const float* __restrict__ rel,
    const float* __restrict__ bp,  const short* __restrict__ img,
    float* __restrict__ out) {
  __shared__ __align__(16) short lds[8*9984];        // 159,744 B -> 1 WG/CU

  const int tid  = threadIdx.x;
  const int lane = tid & 63;
  const int wv   = tid >> 6;
  short* myl   = lds + wv*9984;
  short* featL = myl;                                // 3 x [32][72] = 6912
  short* hL    = myl + 6912;                         // [32][80] = 2560
  short* btL   = myl + 9472;                         // [32][16] = 512

  const int cl  = lane & 15;
  const int g   = lane >> 4;
  const int rw0 = blockIdx.x*256 + wv*32;
  const short8 zz = {0,0,0,0,0,0,0,0};
  const unsigned long long img_u  = (unsigned long long)img;
  const unsigned long long pose_u = (unsigned long long)pose;
  const unsigned long long rel_u  = (unsigned long long)rel;
  const unsigned voff = (unsigned)lane << 4;
  const int btr = lane >> 1, btq = lane & 1;
  const unsigned btProw = (unsigned)((rw0 + btr)*864);
  const unsigned btRrow = (unsigned)((rw0 + btr)*288);

  short8 fw1[15], fw2[12];
  float d0, d1, d2, d3, d4, d5, d6, d7;

  // ---- prologue: bt[joint 0] + bias vector (compiler loads, pre-asm) ----
  {
    const float* pb = pose + (size_t)(rw0 + btr)*216;
    const float* rb = rel  + (size_t)(rw0 + btr)*72;
    short8 w;
    if (btq == 0) {
      w = pk8(*(const f32x4*)pb, *(const f32x4*)(pb + 4));
    } else {
      float r0 = rb[0], r1 = rb[1], r2 = rb[2];
      float nv = sqrtf(r0*r0 + r1*r1 + r2*r2);
      w[0]=sbf(pb[8]); w[1]=sbf(r0); w[2]=sbf(r1); w[3]=sbf(r2);
      w[4]=sbf(nv); w[5]=(short)0x3F80; w[6]=0; w[7]=0;   // col13 = 1.0
    }
    *(short8*)(btL + btr*16 + btq*8) = w;
  }
  f32x4 bpv[4];
#pragma unroll
  for (int nt = 0; nt < 4; ++nt) bpv[nt] = *(const f32x4*)(bp + nt*16 + g*4);

  // ---- root: WpT (A) x bonefeat (B) -> feat slot 2 ----
  f32x4 racc[2][4] = {};
  {
    const float* pr0 = pose + (size_t)(rw0 + cl)*216;
    const float* rr0 = rel  + (size_t)(rw0 + cl)*72;
    const float* pr1 = pose + (size_t)(rw0 + 16 + cl)*216;
    const float* rr1 = rel  + (size_t)(rw0 + 16 + cl)*72;
    const short8* fpg = (const short8*)(img + FP_OFF) + lane;
    short8 av0[9], av1[9];
#pragma unroll
    for (int s = 0; s < 9; ++s) {
      int k0 = s*32 + g*8;
      const float* s0 = (k0 < 216) ? (pr0 + k0) : (rr0 + (k0 - 216));
      const float* s1 = (k0 < 216) ? (pr1 + k0) : (rr1 + (k0 - 216));
      av0[s] = pk8(*(const f32x4*)s0, *(const f32x4*)(s0 + 4));
      av1[s] = pk8(*(const f32x4*)s1, *(const f32x4*)(s1 + 4));
    }
#pragma unroll
    for (int nt = 0; nt < 4; ++nt) {
      short8 fwp[9];
#pragma unroll
      for (int s = 0; s < 9; ++s) fwp[s] = fpg[(nt*9 + s)*64];
#pragma unroll
      for (int s = 0; s < 9; ++s) {
        racc[0][nt] = MFMA(fwp[s], av0[s], racc[0][nt]);
        racc[1][nt] = MFMA(fwp[s], av1[s], racc[1][nt]);
      }
    }
  }
#pragma unroll
  for (int nt = 0; nt < 4; ++nt) {
#pragma unroll
    for (int m = 0; m < 2; ++m) {
      f32x4 v = racc[m][nt];
      v[0]+=bpv[nt][0]; v[1]+=bpv[nt][1]; v[2]+=bpv[nt][2]; v[3]+=bpv[nt][3];
      *(s4*)(featL + 2*2304 + (m*16 + cl)*72 + nt*16 + g*4) = pk4(v);
    }
  }

  ISSUE_W1(0);                                       // first asm VMEM; census 15

  // ---- main DFS loop ----
#pragma unroll 1
  for (int p = 0; p < NJ; ++p) {
    const int j  = ORD[p];
    const int ps = PSL[p];
    const int ss = SSL[p];
    const int jn = (p < NJ-1) ? ORD[p+1] : 0;

    __builtin_amdgcn_s_barrier();                    // phase-lock (raw, no drain)

    // B-fragments from LDS (lgkm only): x[k][batch]
    const short* fb0 = featL + ps*2304 + cl*72;
    const short* fb1 = featL + ps*2304 + (16 + cl)*72;
    short8 a0[2], a1[2], a2[2];
    a0[0] = (g < 2) ? *(const short8*)(btL + cl*16 + g*8)
                    : *(const short8*)(fb0 + (g-2)*8);
    a0[1] = (g < 2) ? *(const short8*)(btL + (16+cl)*16 + g*8)
                    : *(const short8*)(fb1 + (g-2)*8);
    a1[0] = *(const short8*)(fb0 + 16 + g*8);
    a1[1] = *(const short8*)(fb1 + 16 + g*8);
    a2[0] = (g < 2) ? *(const short8*)(fb0 + 48 + g*8) : zz;
    a2[1] = (g < 2) ? *(const short8*)(fb1 + 48 + g*8) : zz;

    // A: bt(jn) dwords + W2(j) x4s
    const unsigned long long aA =
        btq ? (rel_u  + btRrow + (unsigned)(jn ? jn*12 - 4 : 0))
            : (pose_u + btProw + (unsigned)(jn*36));
    const unsigned vB = btProw + (unsigned)(jn*36) + (btq ? 20u : 16u);
    ISSUE_BTW2(j);

    // C: retire W1[j] only
    if (p == 0) { WAITV(20); } else { WAITV(28); }

    // D: GEMM1 swapped — lane gets h[n=nt*16+g*4+r][batch=cl]
#pragma unroll
    for (int nt = 0; nt < 5; ++nt) {
      f32x4 c0 = {0,0,0,0}, c1 = {0,0,0,0};
      c0 = MFMA(fw1[nt*3+0], a0[0], c0);  c1 = MFMA(fw1[nt*3+0], a0[1], c1);
      c0 = MFMA(fw1[nt*3+1], a1[0], c0);  c1 = MFMA(fw1[nt*3+1], a1[1], c1);
      c0 = MFMA(fw1[nt*3+2], a2[0], c0);  c1 = MFMA(fw1[nt*3+2], a2[1], c1);
      *(s4*)(hL + cl*80 + nt*16 + g*4)        = pk4(relu4(c0));
      *(s4*)(hL + (16 + cl)*80 + nt*16 + g*4) = pk4(relu4(c1));
    }
    // E: h B-fragments (lgkm)
    short8 h0[2], h1[2], h2[2];
#pragma unroll
    for (int m = 0; m < 2; ++m) {
      const short* hb = hL + (m*16 + cl)*80;
      h0[m] = *(const short8*)(hb + g*8);
      h1[m] = *(const short8*)(hb + 32 + g*8);
      h2[m] = (g < 2) ? *(const short8*)(hb + 64 + g*8) : zz;  // incl h[77]=1 -> b2
    }

    ISSUE_W1(jn);                                    // F: census 15
    WAITV(15);                                       // H: retire stores + bt/W2

    // decode bt(jn) -> btL (col13 = 1.0)
    {
      f32x4 lo = {d0, d1, d2, d3}, hi = {d4, d5, d6, d7};
      short8 wA = pk8(lo, hi);                       // btq=0: pose f0..f7
      float r0 = jn ? d1 : d0;                       // btq=1: rel r0..r2
      float r1 = jn ? d2 : d1;
      float r2 = jn ? d3 : d2;
      float nv = sqrtf(r0*r0 + r1*r1 + r2*r2);
      short8 wB;
      wB[0]=sbf(d7);   wB[1]=sbf(r0); wB[2]=sbf(r1); wB[3]=sbf(r2);
      wB[4]=sbf(nv); wB[5]=(short)0x3F80; wB[6]=0; wB[7]=0;
      short8 w = btq ? wB : wA;
      *(short8*)(btL + btr*16 + btq*8) = w;
    }

    // I: GEMM2 swapped — coalesced 16B stores + packed feat writes
#pragma unroll
    for (int nt = 0; nt < 4; ++nt) {
      f32x4 c0 = {0,0,0,0}, c1 = {0,0,0,0};
      c0 = MFMA(fw2[nt*3+0], h0[0], c0);  c1 = MFMA(fw2[nt*3+0], h0[1], c1);
      c0 = MFMA(fw2[nt*3+1], h1[0], c0);  c1 = MFMA(fw2[nt*3+1], h1[1], c1);
      c0 = MFMA(fw2[nt*3+2], h2[0], c0);  c1 = MFMA(fw2[nt*3+2], h2[1], c1);
      f32x4 v0 = relu4(c0), v1 = relu4(c1);
      float* o0 = out + (size_t)(rw0 + cl)*1536      + (size_t)j*64 + nt*16 + g*4;
      float* o1 = out + (size_t)(rw0 + 16 + cl)*1536 + (size_t)j*64 + nt*16 + g*4;
      __builtin_nontemporal_store(v0, (f32x4*)o0);
      __builtin_nontemporal_store(v1, (f32x4*)o1);
      if (ss >= 0) {
        *(s4*)(featL + ss*2304 + cl*72 + nt*16 + g*4)        = pk4(v0);
        *(s4*)(featL + ss*2304 + (16 + cl)*72 + nt*16 + g*4) = pk4(v1);
      }
    }
  }
}

extern "C" void kernel_launch(void* const* d_in, const int* in_sizes, int n_in,
                              void* d_out, int out_size, void* d_ws, size_t ws_size,
                              hipStream_t stream) {
  const float* pose = (const float*)d_in[0];
  const float* rel  = (const float*)d_in[1];
  const float* Wp   = (const float*)d_in[2];
  const float* bp   = (const float*)d_in[3];
  const float* W1   = (const float*)d_in[4];
  const float* b1   = (const float*)d_in[5];
  const float* W2   = (const float*)d_in[6];
  const float* b2   = (const float*)d_in[7];
  float* outp = (float*)d_out;
  short* img  = (short*)d_ws;
  const int Bn = in_sizes[0] / 216;
  prep_kernel<<<(IMG_SHORTS + 255)/256, 256, 0, stream>>>(W1, W2, Wp, b1, b2, img);
  enc_kernel<<<Bn/256, 512, 0, stream>>>(pose, rel, bp, img, outp);
}

// Round 16
// 152.871 us; speedup vs baseline: 1.0688x; 1.0474x over previous
//
#include <hip/hip_runtime.h>
#include <hip/hip_bf16.h>
#include <math.h>

typedef __attribute__((ext_vector_type(8))) short short8;
typedef __attribute__((ext_vector_type(4))) short s4;
typedef __attribute__((ext_vector_type(4))) float f32x4;

#define NJ 24

// ---- ws image: per-fragment 1KB blocks (64 lanes x 16B), lane-major ----
// W1image row 13 = b1 (bias-as-K: x[13]=1), row13 col77 = 1.0 (h[77] regenerator)
// W2image row 77 = b2
#define F1_J   7680
#define F2_OFF (NJ*F1_J)
#define F2_J   6144
#define FP_OFF (F2_OFF + NJ*F2_J)
#define IMG_SHORTS (FP_OFF + 36*512)        // 350208 shorts = 700416 B

// operand-swapped MFMA: A = weights [n][k], B = activations [k][batch]
#define MFMA(A,B,C) __builtin_amdgcn_mfma_f32_16x16x32_bf16((A),(B),(C),0,0,0)

__constant__ int ORD[24] = {0,1,4,7,10, 2,5,8,11, 3,6,9, 12,15, 13,16,18,20,22, 14,17,19,21,23};
__constant__ int PSL[24] = {2,0,1,1,1,  0,1,1,1,  0,0,0,  0,1,   0,1,1,1,1,    0,0,0,0,0};
__constant__ int SSL[24] = {0,1,1,1,-1, 1,1,1,-1, 0,0,0,  1,-1,  1,1,1,1,-1,   0,0,0,0,-1};

__device__ __forceinline__ short f2bf(float f) {
  union { float f; unsigned u; } v; v.f = f;
  unsigned r = v.u + 0x7FFFu + ((v.u >> 16) & 1u);
  return (short)(r >> 16);
}
__device__ __forceinline__ short sbf(float f) {
  __hip_bfloat16 h = __float2bfloat16(f);
  return *reinterpret_cast<short*>(&h);
}
__device__ __forceinline__ short8 pk8(f32x4 lo, f32x4 hi) {
  union { short8 s; unsigned u[4]; } r;
  asm("v_cvt_pk_bf16_f32 %0, %1, %2" : "=v"(r.u[0]) : "v"(lo[0]), "v"(lo[1]));
  asm("v_cvt_pk_bf16_f32 %0, %1, %2" : "=v"(r.u[1]) : "v"(lo[2]), "v"(lo[3]));
  asm("v_cvt_pk_bf16_f32 %0, %1, %2" : "=v"(r.u[2]) : "v"(hi[0]), "v"(hi[1]));
  asm("v_cvt_pk_bf16_f32 %0, %1, %2" : "=v"(r.u[3]) : "v"(hi[2]), "v"(hi[3]));
  return r.s;
}
__device__ __forceinline__ s4 pk4(f32x4 v) {
  union { s4 s; unsigned u[2]; } r;
  asm("v_cvt_pk_bf16_f32 %0, %1, %2" : "=v"(r.u[0]) : "v"(v[0]), "v"(v[1]));
  asm("v_cvt_pk_bf16_f32 %0, %1, %2" : "=v"(r.u[1]) : "v"(v[2]), "v"(v[3]));
  return r.s;
}
__device__ __forceinline__ f32x4 relu4(f32x4 v) {
  f32x4 r; r[0]=fmaxf(v[0],0.f); r[1]=fmaxf(v[1],0.f);
  r[2]=fmaxf(v[2],0.f); r[3]=fmaxf(v[3],0.f); return r;
}

__global__ __launch_bounds__(256) void prep_kernel(
    const float* __restrict__ W1, const float* __restrict__ W2,
    const float* __restrict__ Wp, const float* __restrict__ b1,
    const float* __restrict__ b2, short* __restrict__ img) {
  int t = blockIdx.x * 256 + threadIdx.x;
  if (t >= IMG_SHORTS) return;
  float v = 0.f;
  if (t < F2_OFF) {
    int i = t / F1_J, r = t % F1_J;
    int blk = r >> 9, q = r & 511;
    int ln = q >> 3, e = q & 7;
    int nt = blk / 3, s = blk - nt*3;
    int n  = nt*16 + (ln & 15);
    int kp = s*32 + (ln >> 4)*8 + e;
    if (kp == 13) {
      v = (n < 77) ? b1[i*77 + n] : (n == 77 ? 1.f : 0.f);
    } else if (n < 77) {
      if (kp < 13)                  v = W1[i*5929 + kp*77 + n];
      else if (kp >= 16 && kp < 80) v = W1[i*5929 + (kp-3)*77 + n];
    }
  } else if (t < FP_OFF) {
    int u = t - F2_OFF;
    int i = u / F2_J, r = u % F2_J;
    int blk = r >> 9, q = r & 511;
    int ln = q >> 3, e = q & 7;
    int nt = blk / 3, s = blk - nt*3;
    int n  = nt*16 + (ln & 15);
    int k  = s*32 + (ln >> 4)*8 + e;
    if (k < 77)       v = W2[i*4928 + k*64 + n];
    else if (k == 77) v = b2[i*64 + n];
  } else {
    int u = t - FP_OFF;
    int blk = u >> 9, q = u & 511;
    int ln = q >> 3, e = q & 7;
    int nt = blk / 9, s = blk - nt*9;
    int n  = nt*16 + (ln & 15);
    int kp = s*32 + (ln >> 4)*8 + e;
    int j, w;
    if (kp < 216) { j = kp / 9;       w = kp % 9; }
    else          { j = (kp-216) / 3; w = 9 + (kp-216) % 3; }
    v = Wp[(j*12 + w)*64 + n];
  }
  img[t] = f2bf(v);
}

// 15 W1 fragment loads into named array (asm-pinned)
#define ISSUE_W1_INTO(ARR, JN) do { \
  unsigned long long _b = img_u + (unsigned long long)(JN)*15360ull; \
  asm volatile( \
    "global_load_dwordx4 %0, %15, %16\n"  "global_load_dwordx4 %1, %15, %16 offset:1024\n" \
    "global_load_dwordx4 %2, %15, %16 offset:2048\n" "global_load_dwordx4 %3, %15, %16 offset:3072\n" \
    "global_load_dwordx4 %4, %15, %17\n"  "global_load_dwordx4 %5, %15, %17 offset:1024\n" \
    "global_load_dwordx4 %6, %15, %17 offset:2048\n" "global_load_dwordx4 %7, %15, %17 offset:3072\n" \
    "global_load_dwordx4 %8, %15, %18\n"  "global_load_dwordx4 %9, %15, %18 offset:1024\n" \
    "global_load_dwordx4 %10, %15, %18 offset:2048\n" "global_load_dwordx4 %11, %15, %18 offset:3072\n" \
    "global_load_dwordx4 %12, %15, %19\n" "global_load_dwordx4 %13, %15, %19 offset:1024\n" \
    "global_load_dwordx4 %14, %15, %19 offset:2048\n" \
    : "=&v"(ARR[0]),"=&v"(ARR[1]),"=&v"(ARR[2]),"=&v"(ARR[3]),"=&v"(ARR[4]), \
      "=&v"(ARR[5]),"=&v"(ARR[6]),"=&v"(ARR[7]),"=&v"(ARR[8]),"=&v"(ARR[9]), \
      "=&v"(ARR[10]),"=&v"(ARR[11]),"=&v"(ARR[12]),"=&v"(ARR[13]),"=&v"(ARR[14]) \
    : "v"(voff), "s"(_b), "s"(_b+4096ull), "s"(_b+8192ull), "s"(_b+12288ull) \
    : "memory"); \
} while(0)

// 12 W2(J) x4 loads + 8 bt dword loads (joint JB, addrs aA/vB precomputed). Census 20.
#define ISSUE_BTW2(J) do { \
  unsigned long long _b = img_u + 368640ull + (unsigned long long)(J)*12288ull; \
  asm volatile( \
    "global_load_dwordx4 %8, %23, %24\n"  "global_load_dwordx4 %9, %23, %24 offset:1024\n" \
    "global_load_dwordx4 %10, %23, %24 offset:2048\n" "global_load_dwordx4 %11, %23, %24 offset:3072\n" \
    "global_load_dwordx4 %12, %23, %25\n" "global_load_dwordx4 %13, %23, %25 offset:1024\n" \
    "global_load_dwordx4 %14, %23, %25 offset:2048\n" "global_load_dwordx4 %15, %23, %25 offset:3072\n" \
    "global_load_dwordx4 %16, %23, %26\n" "global_load_dwordx4 %17, %23, %26 offset:1024\n" \
    "global_load_dwordx4 %18, %23, %26 offset:2048\n" "global_load_dwordx4 %19, %23, %26 offset:3072\n" \
    "global_load_dword %0, %20, off\n" \
    "global_load_dword %1, %20, off offset:4\n" \
    "global_load_dword %2, %20, off offset:8\n" \
    "global_load_dword %3, %20, off offset:12\n" \
    "global_load_dword %4, %21, %22\n" \
    "global_load_dword %5, %21, %22 offset:4\n" \
    "global_load_dword %6, %21, %22 offset:8\n" \
    "global_load_dword %7, %21, %22 offset:12\n" \
    : "=&v"(d0),"=&v"(d1),"=&v"(d2),"=&v"(d3),"=&v"(d4),"=&v"(d5),"=&v"(d6),"=&v"(d7), \
      "=&v"(fw2[0]),"=&v"(fw2[1]),"=&v"(fw2[2]),"=&v"(fw2[3]),"=&v"(fw2[4]),"=&v"(fw2[5]), \
      "=&v"(fw2[6]),"=&v"(fw2[7]),"=&v"(fw2[8]),"=&v"(fw2[9]),"=&v"(fw2[10]),"=&v"(fw2[11]) \
    : "v"(aA), "v"(vB), "s"(pose_u), "v"(voff), \
      "s"(_b), "s"(_b+4096ull), "s"(_b+8192ull) \
    : "memory"); \
} while(0)

#define WAITV(N) do { asm volatile("s_waitcnt vmcnt(" #N ")" ::: "memory"); \
                      __builtin_amdgcn_sched_barrier(0); } while(0)

// One joint body. FW = W1 fragment buffer for this parity.
// CWAIT literal: 15 (p==0) / 43 (steady).
// Steady census at C: [W1(p):15 | st(p-1):8 | W2(p)+bt(p+1):20 | W1(p+1):15] = 58.
#define BODY(P, FW, CWAIT) do { \
    const int j  = ORD[P]; \
    const int ps = PSL[P]; \
    const int ss = SSL[P]; \
    const int jw2 = ((P)+1 < NJ) ? ORD[(P)+1] : 0; \
    const int jd  = ((P)+1 < NJ) ? ORD[(P)+1] : 0; \
    const int jb  = ((P)+2 < NJ) ? ORD[(P)+2] : 0; \
    const int jw1 = ((P)+2 < NJ) ? ORD[(P)+2] : 0; \
    /* B: activation fragments (LDS, lgkm only) */ \
    const short* fb0 = featL + ps*2304 + cl*72; \
    const short* fb1 = featL + ps*2304 + (16 + cl)*72; \
    short8 a0[2], a1[2], a2[2]; \
    a0[0] = (g < 2) ? *(const short8*)(btL + cl*16 + g*8) \
                    : *(const short8*)(fb0 + (g-2)*8); \
    a0[1] = (g < 2) ? *(const short8*)(btL + (16+cl)*16 + g*8) \
                    : *(const short8*)(fb1 + (g-2)*8); \
    a1[0] = *(const short8*)(fb0 + 16 + g*8); \
    a1[1] = *(const short8*)(fb1 + 16 + g*8); \
    a2[0] = (g < 2) ? *(const short8*)(fb0 + 48 + g*8) : zz; \
    a2[1] = (g < 2) ? *(const short8*)(fb1 + 48 + g*8) : zz; \
    /* C: retire W1[j] (2 iterations of flight) */ \
    WAITV(CWAIT); \
    /* D: GEMM1 */ \
    _Pragma("unroll") \
    for (int nt = 0; nt < 5; ++nt) { \
      f32x4 c0 = {0,0,0,0}, c1 = {0,0,0,0}; \
      c0 = MFMA(FW[nt*3+0], a0[0], c0);  c1 = MFMA(FW[nt*3+0], a0[1], c1); \
      c0 = MFMA(FW[nt*3+1], a1[0], c0);  c1 = MFMA(FW[nt*3+1], a1[1], c1); \
      c0 = MFMA(FW[nt*3+2], a2[0], c0);  c1 = MFMA(FW[nt*3+2], a2[1], c1); \
      *(s4*)(hL + cl*80 + nt*16 + g*4)        = pk4(relu4(c0)); \
      *(s4*)(hL + (16 + cl)*80 + nt*16 + g*4) = pk4(relu4(c1)); \
    } \
    /* E: h fragments */ \
    short8 h0[2], h1[2], h2[2]; \
    _Pragma("unroll") \
    for (int m = 0; m < 2; ++m) { \
      const short* hb = hL + (m*16 + cl)*80; \
      h0[m] = *(const short8*)(hb + g*8); \
      h1[m] = *(const short8*)(hb + 32 + g*8); \
      h2[m] = (g < 2) ? *(const short8*)(hb + 64 + g*8) : zz; \
    } \
    /* C2: retire st(p-1) + W2(j) + bt(jd) (1 iteration of flight) */ \
    WAITV(15); \
    /* decode bt(jd) -> btL */ \
    { \
      f32x4 lo = {d0, d1, d2, d3}, hi = {d4, d5, d6, d7}; \
      short8 wA = pk8(lo, hi); \
      float r0 = jd ? d1 : d0; \
      float r1 = jd ? d2 : d1; \
      float r2 = jd ? d3 : d2; \
      float nv = sqrtf(r0*r0 + r1*r1 + r2*r2); \
      short8 wB; \
      wB[0]=sbf(d7);   wB[1]=sbf(r0); wB[2]=sbf(r1); wB[3]=sbf(r2); \
      wB[4]=sbf(nv); wB[5]=(short)0x3F80; wB[6]=0; wB[7]=0; \
      short8 w = btq ? wB : wA; \
      *(short8*)(btL + btr*16 + btq*8) = w; \
    } \
    /* I: GEMM2 + coalesced stores + feat writes */ \
    _Pragma("unroll") \
    for (int nt = 0; nt < 4; ++nt) { \
      f32x4 c0 = {0,0,0,0}, c1 = {0,0,0,0}; \
      c0 = MFMA(fw2[nt*3+0], h0[0], c0);  c1 = MFMA(fw2[nt*3+0], h0[1], c1); \
      c0 = MFMA(fw2[nt*3+1], h1[0], c0);  c1 = MFMA(fw2[nt*3+1], h1[1], c1); \
      c0 = MFMA(fw2[nt*3+2], h2[0], c0);  c1 = MFMA(fw2[nt*3+2], h2[1], c1); \
      f32x4 v0 = relu4(c0), v1 = relu4(c1); \
      float* o0 = out + (size_t)(rw0 + cl)*1536      + (size_t)j*64 + nt*16 + g*4; \
      float* o1 = out + (size_t)(rw0 + 16 + cl)*1536 + (size_t)j*64 + nt*16 + g*4; \
      __builtin_nontemporal_store(v0, (f32x4*)o0); \
      __builtin_nontemporal_store(v1, (f32x4*)o1); \
      if (ss >= 0) { \
        *(s4*)(featL + ss*2304 + cl*72 + nt*16 + g*4)        = pk4(v0); \
        *(s4*)(featL + ss*2304 + (16 + cl)*72 + nt*16 + g*4) = pk4(v1); \
      } \
    } \
    /* F: issue W2(jw2)+bt(jb), then W1(jw1) into FW (free until D(P+2)) */ \
    { \
      const unsigned long long aA = \
          btq ? (rel_u  + btRrow + (unsigned)(jb ? jb*12 - 4 : 0)) \
              : (pose_u + btProw + (unsigned)(jb*36)); \
      const unsigned vB = btProw + (unsigned)(jb*36) + (btq ? 20u : 16u); \
      ISSUE_BTW2(jw2); \
    } \
    ISSUE_W1_INTO(FW, jw1); \
  } while(0)

// 256 threads = 4 waves; wave owns 32 rows + whole tree. ZERO barriers.
// 2-deep W1 pipeline (ping-pong by joint parity), 1-deep W2/bt, stores never waited.
__global__ __launch_bounds__(256, 2) void enc_kernel(
    const float* __restrict__ pose, const float* __restrict__ rel,
    const float* __restrict__ bp,  const short* __restrict__ img,
    float* __restrict__ out) {
  __shared__ __align__(16) short lds[4*10240];       // 81,920 B -> 2 WG/CU

  const int tid  = threadIdx.x;
  const int lane = tid & 63;
  const int wv   = tid >> 6;
  short* myl   = lds + wv*10240;
  short* featL = myl;                                // 3 x [32][72] = 6912
  short* hL    = myl + 6912;                         // [32][80] = 2560
  short* btL   = myl + 9472;                         // [32][16] (+pad)

  const int cl  = lane & 15;
  const int g   = lane >> 4;
  const int rw0 = blockIdx.x*128 + wv*32;
  const short8 zz = {0,0,0,0,0,0,0,0};
  const unsigned long long img_u  = (unsigned long long)img;
  const unsigned long long pose_u = (unsigned long long)pose;
  const unsigned long long rel_u  = (unsigned long long)rel;
  const unsigned voff = (unsigned)lane << 4;
  const int btr = lane >> 1, btq = lane & 1;
  const unsigned btProw = (unsigned)((rw0 + btr)*864);
  const unsigned btRrow = (unsigned)((rw0 + btr)*288);

  short8 fw1a[15], fw1b[15], fw2[12];
  float d0, d1, d2, d3, d4, d5, d6, d7;

  // ---- prologue: bt[joint 0] + bias vector (compiler loads, pre-asm) ----
  {
    const float* pb = pose + (size_t)(rw0 + btr)*216;
    const float* rb = rel  + (size_t)(rw0 + btr)*72;
    short8 w;
    if (btq == 0) {
      w = pk8(*(const f32x4*)pb, *(const f32x4*)(pb + 4));
    } else {
      float r0 = rb[0], r1 = rb[1], r2 = rb[2];
      float nv = sqrtf(r0*r0 + r1*r1 + r2*r2);
      w[0]=sbf(pb[8]); w[1]=sbf(r0); w[2]=sbf(r1); w[3]=sbf(r2);
      w[4]=sbf(nv); w[5]=(short)0x3F80; w[6]=0; w[7]=0;   // col13 = 1.0
    }
    *(short8*)(btL + btr*16 + btq*8) = w;
  }
  f32x4 bpv[4];
#pragma unroll
  for (int nt = 0; nt < 4; ++nt) bpv[nt] = *(const f32x4*)(bp + nt*16 + g*4);

  // ---- root: WpT (A) x bonefeat (B) -> feat slot 2 ----
  f32x4 racc[2][4] = {};
  {
    const float* pr0 = pose + (size_t)(rw0 + cl)*216;
    const float* rr0 = rel  + (size_t)(rw0 + cl)*72;
    const float* pr1 = pose + (size_t)(rw0 + 16 + cl)*216;
    const float* rr1 = rel  + (size_t)(rw0 + 16 + cl)*72;
    const short8* fpg = (const short8*)(img + FP_OFF) + lane;
    short8 av0[9], av1[9];
#pragma unroll
    for (int s = 0; s < 9; ++s) {
      int k0 = s*32 + g*8;
      const float* s0 = (k0 < 216) ? (pr0 + k0) : (rr0 + (k0 - 216));
      const float* s1 = (k0 < 216) ? (pr1 + k0) : (rr1 + (k0 - 216));
      av0[s] = pk8(*(const f32x4*)s0, *(const f32x4*)(s0 + 4));
      av1[s] = pk8(*(const f32x4*)s1, *(const f32x4*)(s1 + 4));
    }
#pragma unroll
    for (int nt = 0; nt < 4; ++nt) {
      short8 fwp[9];
#pragma unroll
      for (int s = 0; s < 9; ++s) fwp[s] = fpg[(nt*9 + s)*64];
#pragma unroll
      for (int s = 0; s < 9; ++s) {
        racc[0][nt] = MFMA(fwp[s], av0[s], racc[0][nt]);
        racc[1][nt] = MFMA(fwp[s], av1[s], racc[1][nt]);
      }
    }
  }
#pragma unroll
  for (int nt = 0; nt < 4; ++nt) {
#pragma unroll
    for (int m = 0; m < 2; ++m) {
      f32x4 v = racc[m][nt];
      v[0]+=bpv[nt][0]; v[1]+=bpv[nt][1]; v[2]+=bpv[nt][2]; v[3]+=bpv[nt][3];
      *(s4*)(featL + 2*2304 + (m*16 + cl)*72 + nt*16 + g*4) = pk4(v);
    }
  }

  // ---- prologue issue: [W2(j0):12, bt(ORD[1]):8] [W1a(j0):15] [W1b(ORD[1]):15] = 50
  {
    const int jb = ORD[1];
    const unsigned long long aA =
        btq ? (rel_u  + btRrow + (unsigned)(jb*12 - 4))
            : (pose_u + btProw + (unsigned)(jb*36));
    const unsigned vB = btProw + (unsigned)(jb*36) + (btq ? 20u : 16u);
    ISSUE_BTW2(0);
  }
  ISSUE_W1_INTO(fw1a, 0);
  ISSUE_W1_INTO(fw1b, ORD[1]);

  // ---- main DFS loop: peel p=0,1 then 11 double-bodies ----
  BODY(0, fw1a, 15);
  BODY(1, fw1b, 43);
#pragma unroll 1
  for (int q = 1; q < 12; ++q) {
    const int p = 2*q;
    BODY(p,     fw1a, 43);
    BODY(p + 1, fw1b, 43);
  }
}

extern "C" void kernel_launch(void* const* d_in, const int* in_sizes, int n_in,
                              void* d_out, int out_size, void* d_ws, size_t ws_size,
                              hipStream_t stream) {
  const float* pose = (const float*)d_in[0];
  const float* rel  = (const float*)d_in[1];
  const float* Wp   = (const float*)d_in[2];
  const float* bp   = (const float*)d_in[3];
  const float* W1   = (const float*)d_in[4];
  const float* b1   = (const float*)d_in[5];
  const float* W2   = (const float*)d_in[6];
  const float* b2   = (const float*)d_in[7];
  float* outp = (float*)d_out;
  short* img  = (short*)d_ws;
  const int Bn = in_sizes[0] / 216;
  prep_kernel<<<(IMG_SHORTS + 255)/256, 256, 0, stream>>>(W1, W2, Wp, b1, b2, img);
  enc_kernel<<<Bn/128, 256, 0, stream>>>(pose, rel, bp, img, outp);
}

// Round 19
// 149.015 us; speedup vs baseline: 1.0964x; 1.0259x over previous
//
#include <hip/hip_runtime.h>
#include <hip/hip_bf16.h>
#include <math.h>

typedef __attribute__((ext_vector_type(8))) short short8;
typedef __attribute__((ext_vector_type(4))) short s4;
typedef __attribute__((ext_vector_type(4))) float f32x4;

#define NJ 24

// ---- ws image: per-fragment 1KB blocks (64 lanes x 16B), lane-major ----
// W1image row 13 = b1 (bias-as-K: x[13]=1), row13 col77 = 1.0 (h[77] regenerator)
// W2image row 77 = b2
#define F1_J   7680
#define F2_OFF (NJ*F1_J)
#define F2_J   6144
#define FP_OFF (F2_OFF + NJ*F2_J)
#define IMG_SHORTS (FP_OFF + 36*512)        // 350208 shorts = 700416 B

// operand-swapped MFMA: A = weights [n][k], B = activations [k][batch]
#define MFMA(A,B,C) __builtin_amdgcn_mfma_f32_16x16x32_bf16((A),(B),(C),0,0,0)

// DFS order; 2-slot schedule (root prior in slot 1, consumed only at p=0;
// verified by full 24-step simulation over PARENTS)
__constant__ int ORD[24] = {0,1,4,7,10, 2,5,8,11, 3,6,9, 12,15, 13,16,18,20,22, 14,17,19,21,23};
__constant__ int PSL[24] = {1,0,1,1,1,  0,1,1,1,  0,0,0,  0,1,   0,1,1,1,1,    0,0,0,0,0};
__constant__ int SSL[24] = {0,1,1,1,-1, 1,1,1,-1, 0,0,0,  1,-1,  1,1,1,1,-1,   0,0,0,0,-1};

__device__ __forceinline__ short f2bf(float f) {
  union { float f; unsigned u; } v; v.f = f;
  unsigned r = v.u + 0x7FFFu + ((v.u >> 16) & 1u);
  return (short)(r >> 16);
}
__device__ __forceinline__ short sbf(float f) {
  __hip_bfloat16 h = __float2bfloat16(f);
  return *reinterpret_cast<short*>(&h);
}
__device__ __forceinline__ short8 pk8(f32x4 lo, f32x4 hi) {
  union { short8 s; unsigned u[4]; } r;
  asm("v_cvt_pk_bf16_f32 %0, %1, %2" : "=v"(r.u[0]) : "v"(lo[0]), "v"(lo[1]));
  asm("v_cvt_pk_bf16_f32 %0, %1, %2" : "=v"(r.u[1]) : "v"(lo[2]), "v"(lo[3]));
  asm("v_cvt_pk_bf16_f32 %0, %1, %2" : "=v"(r.u[2]) : "v"(hi[0]), "v"(hi[1]));
  asm("v_cvt_pk_bf16_f32 %0, %1, %2" : "=v"(r.u[3]) : "v"(hi[2]), "v"(hi[3]));
  return r.s;
}
__device__ __forceinline__ s4 pk4(f32x4 v) {
  union { s4 s; unsigned u[2]; } r;
  asm("v_cvt_pk_bf16_f32 %0, %1, %2" : "=v"(r.u[0]) : "v"(v[0]), "v"(v[1]));
  asm("v_cvt_pk_bf16_f32 %0, %1, %2" : "=v"(r.u[1]) : "v"(v[2]), "v"(v[3]));
  return r.s;
}
__device__ __forceinline__ f32x4 relu4(f32x4 v) {
  f32x4 r; r[0]=fmaxf(v[0],0.f); r[1]=fmaxf(v[1],0.f);
  r[2]=fmaxf(v[2],0.f); r[3]=fmaxf(v[3],0.f); return r;
}

__global__ __launch_bounds__(256) void prep_kernel(
    const float* __restrict__ W1, const float* __restrict__ W2,
    const float* __restrict__ Wp, const float* __restrict__ b1,
    const float* __restrict__ b2, short* __restrict__ img) {
  int t = blockIdx.x * 256 + threadIdx.x;
  if (t >= IMG_SHORTS) return;
  float v = 0.f;
  if (t < F2_OFF) {
    int i = t / F1_J, r = t % F1_J;
    int blk = r >> 9, q = r & 511;
    int ln = q >> 3, e = q & 7;
    int nt = blk / 3, s = blk - nt*3;
    int n  = nt*16 + (ln & 15);
    int kp = s*32 + (ln >> 4)*8 + e;
    if (kp == 13) {
      v = (n < 77) ? b1[i*77 + n] : (n == 77 ? 1.f : 0.f);
    } else if (n < 77) {
      if (kp < 13)                  v = W1[i*5929 + kp*77 + n];
      else if (kp >= 16 && kp < 80) v = W1[i*5929 + (kp-3)*77 + n];
    }
  } else if (t < FP_OFF) {
    int u = t - F2_OFF;
    int i = u / F2_J, r = u % F2_J;
    int blk = r >> 9, q = r & 511;
    int ln = q >> 3, e = q & 7;
    int nt = blk / 3, s = blk - nt*3;
    int n  = nt*16 + (ln & 15);
    int k  = s*32 + (ln >> 4)*8 + e;
    if (k < 77)       v = W2[i*4928 + k*64 + n];
    else if (k == 77) v = b2[i*64 + n];
  } else {
    int u = t - FP_OFF;
    int blk = u >> 9, q = u & 511;
    int ln = q >> 3, e = q & 7;
    int nt = blk / 9, s = blk - nt*9;
    int n  = nt*16 + (ln & 15);
    int kp = s*32 + (ln >> 4)*8 + e;
    int j, w;
    if (kp < 216) { j = kp / 9;       w = kp % 9; }
    else          { j = (kp-216) / 3; w = 9 + (kp-216) % 3; }
    v = Wp[(j*12 + w)*64 + n];
  }
  img[t] = f2bf(v);
}

// 15 W1 fragment loads (asm-pinned, 16B-aligned, in-bounds)
#define ISSUE_W1(JN) do { \
  unsigned long long _b = img_u + (unsigned long long)(JN)*15360ull; \
  asm volatile( \
    "global_load_dwordx4 %0, %15, %16\n"  "global_load_dwordx4 %1, %15, %16 offset:1024\n" \
    "global_load_dwordx4 %2, %15, %16 offset:2048\n" "global_load_dwordx4 %3, %15, %16 offset:3072\n" \
    "global_load_dwordx4 %4, %15, %17\n"  "global_load_dwordx4 %5, %15, %17 offset:1024\n" \
    "global_load_dwordx4 %6, %15, %17 offset:2048\n" "global_load_dwordx4 %7, %15, %17 offset:3072\n" \
    "global_load_dwordx4 %8, %15, %18\n"  "global_load_dwordx4 %9, %15, %18 offset:1024\n" \
    "global_load_dwordx4 %10, %15, %18 offset:2048\n" "global_load_dwordx4 %11, %15, %18 offset:3072\n" \
    "global_load_dwordx4 %12, %15, %19\n" "global_load_dwordx4 %13, %15, %19 offset:1024\n" \
    "global_load_dwordx4 %14, %15, %19 offset:2048\n" \
    : "=&v"(fw1[0]),"=&v"(fw1[1]),"=&v"(fw1[2]),"=&v"(fw1[3]),"=&v"(fw1[4]), \
      "=&v"(fw1[5]),"=&v"(fw1[6]),"=&v"(fw1[7]),"=&v"(fw1[8]),"=&v"(fw1[9]), \
      "=&v"(fw1[10]),"=&v"(fw1[11]),"=&v"(fw1[12]),"=&v"(fw1[13]),"=&v"(fw1[14]) \
    : "v"(voff), "s"(_b), "s"(_b+4096ull), "s"(_b+8192ull), "s"(_b+12288ull) \
    : "memory"); \
} while(0)

// 12 W2(J) x4 loads + 12 bt dword loads (lane = row; aP/aR per-lane 64b vaddr).
// Census: 24. Operand map: %0-%11 bt dwords, %12-%23 W2 frags,
//   %24=aP, %25=aR, %26=voff, %27/%28/%29 = W2 sbase 0/4096/8192.
#define ISSUE_BTW2(J) do { \
  unsigned long long _b = img_u + 368640ull + (unsigned long long)(J)*12288ull; \
  asm volatile( \
    "global_load_dwordx4 %12, %26, %27\n" "global_load_dwordx4 %13, %26, %27 offset:1024\n" \
    "global_load_dwordx4 %14, %26, %27 offset:2048\n" "global_load_dwordx4 %15, %26, %27 offset:3072\n" \
    "global_load_dwordx4 %16, %26, %28\n" "global_load_dwordx4 %17, %26, %28 offset:1024\n" \
    "global_load_dwordx4 %18, %26, %28 offset:2048\n" "global_load_dwordx4 %19, %26, %28 offset:3072\n" \
    "global_load_dwordx4 %20, %26, %29\n" "global_load_dwordx4 %21, %26, %29 offset:1024\n" \
    "global_load_dwordx4 %22, %26, %29 offset:2048\n" "global_load_dwordx4 %23, %26, %29 offset:3072\n" \
    "global_load_dword %0, %24, off\n" \
    "global_load_dword %1, %24, off offset:4\n" \
    "global_load_dword %2, %24, off offset:8\n" \
    "global_load_dword %3, %24, off offset:12\n" \
    "global_load_dword %4, %24, off offset:16\n" \
    "global_load_dword %5, %24, off offset:20\n" \
    "global_load_dword %6, %24, off offset:24\n" \
    "global_load_dword %7, %24, off offset:28\n" \
    "global_load_dword %8, %24, off offset:32\n" \
    "global_load_dword %9, %25, off\n" \
    "global_load_dword %10, %25, off offset:4\n" \
    "global_load_dword %11, %25, off offset:8\n" \
    : "=&v"(d0),"=&v"(d1),"=&v"(d2),"=&v"(d3),"=&v"(d4),"=&v"(d5), \
      "=&v"(d6),"=&v"(d7),"=&v"(d8),"=&v"(d9),"=&v"(d10),"=&v"(d11), \
      "=&v"(fw2[0]),"=&v"(fw2[1]),"=&v"(fw2[2]),"=&v"(fw2[3]),"=&v"(fw2[4]),"=&v"(fw2[5]), \
      "=&v"(fw2[6]),"=&v"(fw2[7]),"=&v"(fw2[8]),"=&v"(fw2[9]),"=&v"(fw2[10]),"=&v"(fw2[11]) \
    : "v"(aP), "v"(aR), "v"(voff), \
      "s"(_b), "s"(_b+4096ull), "s"(_b+8192ull) \
    : "memory"); \
} while(0)

#define WAITV(N) do { asm volatile("s_waitcnt vmcnt(" #N ")" ::: "memory"); \
                      __builtin_amdgcn_sched_barrier(0); } while(0)

// 256 threads = 4 waves; wave owns 64 rows (4 m-tiles) + whole tree. ZERO barriers.
// 1 WG/CU (122,880 B LDS), 1 wave/SIMD. Fragments loaded PER-M inside the GEMM
// loops (register diet: peak ~190 arch VGPRs -> no scratch spills; spills would
// corrupt the vmcnt census, which was R18's failure mode).
// Census/joint: A:24 (W2+bt) | stores:16 | F:15 (W1 next).
//   C = vmcnt(24) retires st(p-1)+W1(p); H = vmcnt(0) retires A. Peak 55.
__global__ __launch_bounds__(256, 1) void enc_kernel(
    const float* __restrict__ pose, const float* __restrict__ rel,
    const float* __restrict__ bp,  const short* __restrict__ img,
    float* __restrict__ out) {
  __shared__ __align__(16) short lds[4*15360];       // 122,880 B -> 1 WG/CU

  const int tid  = threadIdx.x;
  const int lane = tid & 63;
  const int wv   = tid >> 6;
  short* myl   = lds + wv*15360;
  short* featL = myl;                                // 2 slots x [64][72] = 9216
  short* hL    = myl + 9216;                         // [64][80] = 5120
  short* btL   = myl + 14336;                        // [64][16] = 1024

  const int cl  = lane & 15;
  const int g   = lane >> 4;
  const int rw0 = blockIdx.x*256 + wv*64;
  const short8 zz = {0,0,0,0,0,0,0,0};
  const unsigned long long img_u  = (unsigned long long)img;
  const unsigned long long pose_u = (unsigned long long)pose;
  const unsigned long long rel_u  = (unsigned long long)rel;
  const unsigned voff = (unsigned)lane << 4;
  // bt: lane r = row r (64 rows)
  const unsigned long long btP = pose_u + (unsigned long long)(rw0 + lane)*864ull;
  const unsigned long long btR = rel_u  + (unsigned long long)(rw0 + lane)*288ull;

  short8 fw1[15], fw2[12];
  float d0,d1,d2,d3,d4,d5,d6,d7,d8,d9,d10,d11;

  // ---- prologue: bt[joint 0] via compiler loads (lane = row) ----
  {
    const float* pb = pose + (size_t)(rw0 + lane)*216;
    const float* rb = rel  + (size_t)(rw0 + lane)*72;
    float p0=pb[0],p1=pb[1],p2=pb[2],p3=pb[3],p4=pb[4],p5=pb[5],p6=pb[6],p7=pb[7],p8=pb[8];
    float r0=rb[0],r1=rb[1],r2=rb[2];
    float nv = sqrtf(r0*r0 + r1*r1 + r2*r2);
    short8 wlo = pk8((f32x4){p0,p1,p2,p3}, (f32x4){p4,p5,p6,p7});
    short8 whi;
    whi[0]=sbf(p8); whi[1]=sbf(r0); whi[2]=sbf(r1); whi[3]=sbf(r2);
    whi[4]=sbf(nv); whi[5]=(short)0x3F80; whi[6]=0; whi[7]=0;   // col13 = 1.0
    *(short8*)(btL + lane*16)     = wlo;
    *(short8*)(btL + lane*16 + 8) = whi;
  }

  // ---- root: WpT (A) x bonefeat (B) -> feat slot 1 (4 m-tiles) ----
#pragma unroll 1
  for (int m = 0; m < 4; ++m) {
    const float* pr = pose + (size_t)(rw0 + m*16 + cl)*216;
    const float* rr = rel  + (size_t)(rw0 + m*16 + cl)*72;
    const short8* fpg = (const short8*)(img + FP_OFF) + lane;
    short8 av[9];
#pragma unroll
    for (int s = 0; s < 9; ++s) {
      int k0 = s*32 + g*8;
      const float* sp = (k0 < 216) ? (pr + k0) : (rr + (k0 - 216));
      av[s] = pk8(*(const f32x4*)sp, *(const f32x4*)(sp + 4));
    }
#pragma unroll
    for (int nt = 0; nt < 4; ++nt) {
      f32x4 c = {0,0,0,0};
#pragma unroll
      for (int s = 0; s < 9; ++s) c = MFMA(fpg[(nt*9 + s)*64], av[s], c);
      f32x4 bb = *(const f32x4*)(bp + nt*16 + g*4);
      c[0]+=bb[0]; c[1]+=bb[1]; c[2]+=bb[2]; c[3]+=bb[3];
      *(s4*)(featL + 4608 + (m*16 + cl)*72 + nt*16 + g*4) = pk4(c);
    }
  }

  ISSUE_W1(0);                                       // first asm VMEM; census 15

  // ---- main DFS loop ----
#pragma unroll 1
  for (int p = 0; p < NJ; ++p) {
    const int j  = ORD[p];
    const int ps = PSL[p];
    const int ss = SSL[p];
    const int jn = (p < NJ-1) ? ORD[p+1] : 0;        // dummy jn=0 on last iter

    // A: issue W2(j) + bt(jn)  [census 24]
    const unsigned long long aP = btP + (unsigned long long)(jn*36);
    const unsigned long long aR = btR + (unsigned long long)(jn*12);
    ISSUE_BTW2(j);

    // C: retire st(p-1) + W1(p); A stays in flight
    WAITV(24);

    // D: GEMM1, fragments loaded per-m (low register pressure)
#pragma unroll
    for (int m = 0; m < 4; ++m) {
      const short* fb = featL + ps*4608 + (m*16 + cl)*72;
      short8 a0 = (g < 2) ? *(const short8*)(btL + (m*16 + cl)*16 + g*8)
                          : *(const short8*)(fb + (g-2)*8);
      short8 a1 = *(const short8*)(fb + 16 + g*8);
      short8 a2 = (g < 2) ? *(const short8*)(fb + 48 + g*8) : zz;
#pragma unroll
      for (int nt = 0; nt < 5; ++nt) {
        f32x4 c = {0,0,0,0};
        c = MFMA(fw1[nt*3+0], a0, c);
        c = MFMA(fw1[nt*3+1], a1, c);
        c = MFMA(fw1[nt*3+2], a2, c);
        *(s4*)(hL + (m*16 + cl)*80 + nt*16 + g*4) = pk4(relu4(c));
      }
    }

    // H: retire A (W2 + bt) — issued one full GEMM1 phase ago
    WAITV(0);

    // decode bt(jn) -> btL (col13 = 1.0)
    {
      float nv = sqrtf(d9*d9 + d10*d10 + d11*d11);
      short8 wlo = pk8((f32x4){d0,d1,d2,d3}, (f32x4){d4,d5,d6,d7});
      short8 whi;
      whi[0]=sbf(d8); whi[1]=sbf(d9); whi[2]=sbf(d10); whi[3]=sbf(d11);
      whi[4]=sbf(nv); whi[5]=(short)0x3F80; whi[6]=0; whi[7]=0;
      *(short8*)(btL + lane*16)     = wlo;
      *(short8*)(btL + lane*16 + 8) = whi;
    }

    // I: GEMM2, h fragments per-m — 16 coalesced 16B nt stores + feat writes
#pragma unroll
    for (int m = 0; m < 4; ++m) {
      const short* hb = hL + (m*16 + cl)*80;
      short8 h0 = *(const short8*)(hb + g*8);
      short8 h1 = *(const short8*)(hb + 32 + g*8);
      short8 h2 = (g < 2) ? *(const short8*)(hb + 64 + g*8) : zz;  // incl h[77]=1 -> b2
#pragma unroll
      for (int nt = 0; nt < 4; ++nt) {
        f32x4 c = {0,0,0,0};
        c = MFMA(fw2[nt*3+0], h0, c);
        c = MFMA(fw2[nt*3+1], h1, c);
        c = MFMA(fw2[nt*3+2], h2, c);
        f32x4 v = relu4(c);
        float* o = out + (size_t)(rw0 + m*16 + cl)*1536 + (size_t)j*64 + nt*16 + g*4;
        __builtin_nontemporal_store(v, (f32x4*)o);
        if (ss >= 0)
          *(s4*)(featL + ss*4608 + (m*16 + cl)*72 + nt*16 + g*4) = pk4(v);
      }
    }

    // F: issue W1(jn)  [census 15]
    ISSUE_W1(jn);
  }
}

extern "C" void kernel_launch(void* const* d_in, const int* in_sizes, int n_in,
                              void* d_out, int out_size, void* d_ws, size_t ws_size,
                              hipStream_t stream) {
  const float* pose = (const float*)d_in[0];
  const float* rel  = (const float*)d_in[1];
  const float* Wp   = (const float*)d_in[2];
  const float* bp   = (const float*)d_in[3];
  const float* W1   = (const float*)d_in[4];
  const float* b1   = (const float*)d_in[5];
  const float* W2   = (const float*)d_in[6];
  const float* b2   = (const float*)d_in[7];
  float* outp = (float*)d_out;
  short* img  = (short*)d_ws;
  const int Bn = in_sizes[0] / 216;
  prep_kernel<<<(IMG_SHORTS + 255)/256, 256, 0, stream>>>(W1, W2, Wp, b1, b2, img);
  enc_kernel<<<Bn/256, 256, 0, stream>>>(pose, rel, bp, img, outp);
}